// Round 2
// baseline (496.434 us; speedup 1.0000x reference)
//
#include <hip/hip_runtime.h>
#include <math.h>

#define CC   256   // clusters
#define TILE 128   // points per block

// float-index offsets in ws
#define OFF_P     0        // 256 x float4: (mu_x, mu_y, mu_z, alpha)
#define OFF_Q     1024     // 256 x float4: mu_new
#define OFF_M2    2048     // 256 (unused in hot loops, kept for clarity)
#define OFF_S     2304     // 256 S | 256 Ax | 256 Ay | 256 Az  (contiguous 1024)
#define OFF_CD    3328     // 4 doubles: [0]=sumX2 [1]=sumT2 [2]=sumY2 [3]=sumSM2new
#define OFF_CF    3336     // floats: [0]=twok [1]=lgn [6]=sumSlpi [7]=inv2sn2 [8]=sumGL2
#define OFF_TK    3346     // 2 ints: tickets
#define OFF_T2    3348     // N floats: per-point log2-normalizer

__global__ __launch_bounds__(256) void gmm_prep(const float* __restrict__ mu,
                                                const float* __restrict__ w,
                                                const float* __restrict__ sigma,
                                                float* __restrict__ ws)
{
    __shared__ float redA[4], redB[4];
    const int c = threadIdx.x;
    const int lane = c & 63, wid = c >> 6;

    // zero accumulators for this launch (stream-ordered before pass1)
    ws[OFF_S + c] = 0.f; ws[OFF_S + 256 + c] = 0.f;
    ws[OFF_S + 512 + c] = 0.f; ws[OFF_S + 768 + c] = 0.f;
    if (c == 0) {
        double* CD = (double*)(ws + OFF_CD);
        CD[0] = 0.0; CD[1] = 0.0; CD[2] = 0.0; CD[3] = 0.0;
        int* TK = (int*)(ws + OFF_TK);
        TK[0] = 0; TK[1] = 0;
        for (int i = 2; i < 10; ++i) ws[OFF_CF + i] = 0.f;
    }

    float wc = w[c];
    // Zw = logsumexp(w)
    float m = wc;
    #pragma unroll
    for (int off = 32; off > 0; off >>= 1) m = fmaxf(m, __shfl_xor(m, off));
    if (lane == 0) redA[wid] = m;
    __syncthreads();
    m = fmaxf(fmaxf(redA[0], redA[1]), fmaxf(redA[2], redA[3]));
    float e = expf(wc - m);
    #pragma unroll
    for (int off = 32; off > 0; off >>= 1) e += __shfl_xor(e, off);
    if (lane == 0) redB[wid] = e;
    __syncthreads();
    float Zw = m + logf(redB[0] + redB[1] + redB[2] + redB[3]);

    const float L = 1.4426950408889634f;   // log2(e)
    float sig = sigma[0];
    float lgn = 3.0f * (logf(sig) + 0.91893853320467274f);
    float k = L / (2.0f * sig * sig);
    float mx = mu[3*c], my = mu[3*c+1], mz = mu[3*c+2];
    float m2 = mx*mx + my*my + mz*mz;
    float alpha = (wc - Zw - lgn) * L - k * m2;
    ((float4*)(ws + OFF_P))[c] = make_float4(mx, my, mz, alpha);
    ws[OFF_M2 + c] = m2;
    if (c == 0) { ws[OFF_CF + 0] = 2.0f * k; ws[OFF_CF + 1] = lgn; }
}

__global__ __launch_bounds__(256, 8) void gmm_pass1(const float* __restrict__ X,
                                                    float* __restrict__ ws,
                                                    int N, int nblk)
{
    const float4* Pg = (const float4*)(ws + OFF_P);
    float*  Sg  = ws + OFF_S;
    double* CD  = (double*)(ws + OFF_CD);
    float*  CF  = ws + OFF_CF;
    int*    TK  = (int*)(ws + OFF_TK);
    float*  T2g = ws + OFF_T2;

    __shared__ float4 Psh[CC];
    __shared__ float4 XT[TILE];       // (x,y,z, x2 -> T2)
    __shared__ float  pm[256], ps[256];
    __shared__ double redd[2][4];
    __shared__ double red6[6][4];
    __shared__ int    lastFlag;

    const int tid  = threadIdx.x;
    const int pt   = tid & (TILE-1);
    const int half = tid >> 7;
    const int n0   = blockIdx.x * TILE;
    const int NT   = min(TILE, N - n0);
    const float twok = CF[0];

    Psh[tid] = Pg[tid];
    float x2 = 0.f;
    if (half == 0 && pt < NT) {
        const float* xp = X + 3*(size_t)(n0+pt);
        float x = xp[0], y = xp[1], z = xp[2];
        x2 = fmaf(x, x, fmaf(y, y, z*z));
        XT[pt] = make_float4(x, y, z, x2);
    }
    __syncthreads();

    // phase A: 2 threads per point, 128 clusters each
    float m = -3.0e38f, s = 0.f;
    if (pt < NT) {
        float4 xt = XT[pt];
        const int c0 = half * 128;
        #pragma unroll 8
        for (int c = 0; c < 128; ++c) {
            float4 p = Psh[c0 + c];
            float dot = fmaf(xt.x, p.x, fmaf(xt.y, p.y, xt.z * p.z));
            m = fmaxf(m, fmaf(twok, dot, p.w));
        }
        #pragma unroll 8
        for (int c = 0; c < 128; ++c) {
            float4 p = Psh[c0 + c];
            float dot = fmaf(xt.x, p.x, fmaf(xt.y, p.y, xt.z * p.z));
            s += exp2f(fmaf(twok, dot, p.w) - m);
        }
    }
    pm[tid] = m; ps[tid] = s;
    __syncthreads();

    // finalize T2 per point; pack into XT.w; accumulate sumX2/sumT2
    double t2d = 0.0;
    if (half == 0 && pt < NT) {
        float m0 = pm[tid], m1 = pm[tid + 128];
        float M  = fmaxf(m0, m1);
        float ss = ps[tid] * exp2f(m0 - M) + ps[tid + 128] * exp2f(m1 - M);
        float T2 = M + log2f(ss);
        XT[pt].w = T2;
        T2g[n0 + pt] = T2;
        t2d = (double)T2;
    }
    {
        double xd = (double)x2;
        #pragma unroll
        for (int off = 32; off > 0; off >>= 1) { xd += __shfl_xor(xd, off); t2d += __shfl_xor(t2d, off); }
        const int lane = tid & 63, wid = tid >> 6;
        if (lane == 0) { redd[0][wid] = xd; redd[1][wid] = t2d; }
    }
    __syncthreads();
    if (tid == 0) {
        atomicAdd(CD + 0, redd[0][0] + redd[0][1] + redd[0][2] + redd[0][3]);
        atomicAdd(CD + 1, redd[1][0] + redd[1][1] + redd[1][2] + redd[1][3]);
    }

    // phase B: 1 thread per cluster over NT points (lean: 10 VALU + 1 trans)
    float4 p = Psh[tid];
    float S = 0.f, Ax = 0.f, Ay = 0.f, Az = 0.f;
    #pragma unroll 4
    for (int n = 0; n < NT; ++n) {
        float4 xt = XT[n];
        float dot = fmaf(xt.x, p.x, fmaf(xt.y, p.y, xt.z * p.z));
        float g = exp2f(fmaf(twok, dot, p.w) - xt.w);
        S += g;
        Ax = fmaf(g, xt.x, Ax);
        Ay = fmaf(g, xt.y, Ay);
        Az = fmaf(g, xt.z, Az);
    }
    atomicAdd(Sg       + tid, S);
    atomicAdd(Sg + 256 + tid, Ax);
    atomicAdd(Sg + 512 + tid, Ay);
    atomicAdd(Sg + 768 + tid, Az);

    __threadfence();
    if (tid == 0) lastFlag = (atomicAdd(TK + 0, 1) == nblk - 1);
    __syncthreads();
    if (!lastFlag) return;

    // ===== fused pass2 (last block only) =====
    const int c = tid;
    float Sc  = atomicAdd(Sg       + c, 0.0f);
    float Axc = atomicAdd(Sg + 256 + c, 0.0f);
    float Ayc = atomicAdd(Sg + 512 + c, 0.0f);
    float Azc = atomicAdd(Sg + 768 + c, 0.0f);
    float inv = 1.0f / fmaxf(Sc, 1e-37f);
    float mx = Axc * inv, my = Ayc * inv, mz = Azc * inv;
    ((float4*)(ws + OFF_Q))[c] = make_float4(mx, my, mz, 0.f);

    float4 p_ = Psh[c];   // old mu + alpha
    double v0 = (double)Sc;                                            // sumS
    double v1 = (double)Sc * (double)(mx*mx + my*my + mz*mz);          // sum S*||mu_new||^2
    double v2 = (double)Sc * (double)logf(fmaxf(Sc, 1e-37f));          // sum S*logS
    double v3 = (double)Sc * (double)(p_.x*p_.x + p_.y*p_.y + p_.z*p_.z); // sum S*||mu_old||^2
    double v4 = (double)Sc * (double)p_.w;                             // sum S*alpha
    double v5 = (double)(p_.x*Axc + p_.y*Ayc + p_.z*Azc);              // sum mu_old . A

    {
        const int lane = tid & 63, wid = tid >> 6;
        #pragma unroll
        for (int off = 32; off > 0; off >>= 1) {
            v0 += __shfl_xor(v0, off); v1 += __shfl_xor(v1, off); v2 += __shfl_xor(v2, off);
            v3 += __shfl_xor(v3, off); v4 += __shfl_xor(v4, off); v5 += __shfl_xor(v5, off);
        }
        if (lane == 0) { red6[0][wid]=v0; red6[1][wid]=v1; red6[2][wid]=v2;
                         red6[3][wid]=v3; red6[4][wid]=v4; red6[5][wid]=v5; }
    }
    __syncthreads();
    if (tid == 0) {
        double sumS    = red6[0][0]+red6[0][1]+red6[0][2]+red6[0][3];
        double sumSM2  = red6[1][0]+red6[1][1]+red6[1][2]+red6[1][3];
        double sumSlS  = red6[2][0]+red6[2][1]+red6[2][2]+red6[2][3];
        double sumMS   = red6[3][0]+red6[3][1]+red6[3][2]+red6[3][3];
        double sumAS   = red6[4][0]+red6[4][1]+red6[4][2]+red6[4][3];
        double dotMA   = red6[5][0]+red6[5][1]+red6[5][2]+red6[5][3];
        double sumX2   = atomicAdd(CD + 0, 0.0);
        double sumT2   = atomicAdd(CD + 1, 0.0);
        double sumGD2  = sumX2 + sumMS - 2.0 * dotMA;
        double sn2     = sumGD2 / (3.0 * (double)N);
        CF[7] = (float)(1.0 / (2.0 * sn2));
        CF[6] = (float)(sumSlS - sumS * log(sumS));
        CF[8] = (float)(sumAS + (double)twok * dotMA - sumT2);   // sumGL2 (log2 units)
        CD[3] = sumSM2;
    }
}

__global__ __launch_bounds__(256, 8) void gmm_pass3(const float* __restrict__ X,
                                                    float* __restrict__ ws,
                                                    float* __restrict__ out,
                                                    int N, int nblk)
{
    const float4* Pg = (const float4*)(ws + OFF_P);
    const float4* Qg = (const float4*)(ws + OFF_Q);
    double* CD  = (double*)(ws + OFF_CD);
    float*  CF  = ws + OFF_CF;
    int*    TK  = (int*)(ws + OFF_TK);
    float*  T2g = ws + OFF_T2;

    __shared__ float4 Psh[CC], Qsh[CC];
    __shared__ float4 XT[TILE];       // (x,y,z,T2)
    __shared__ float4 Yp[256];
    __shared__ double redd[4];
    __shared__ int    lastFlag;

    const int tid  = threadIdx.x;
    const int pt   = tid & (TILE-1);
    const int half = tid >> 7;
    const int n0   = blockIdx.x * TILE;
    const int NT   = min(TILE, N - n0);
    const float twok = CF[0];

    Psh[tid] = Pg[tid];
    Qsh[tid] = Qg[tid];
    if (half == 0 && pt < NT) {
        const float* xp = X + 3*(size_t)(n0+pt);
        XT[pt] = make_float4(xp[0], xp[1], xp[2], T2g[n0 + pt]);
    }
    __syncthreads();

    float Yx = 0.f, Yy = 0.f, Yz = 0.f;
    if (pt < NT) {
        float4 xt = XT[pt];
        const int c0 = half * 128;
        #pragma unroll 4
        for (int c = 0; c < 128; ++c) {
            float4 p = Psh[c0 + c];
            float dot = fmaf(xt.x, p.x, fmaf(xt.y, p.y, xt.z * p.z));
            float g = exp2f(fmaf(twok, dot, p.w) - xt.w);
            float4 q = Qsh[c0 + c];
            Yx = fmaf(g, q.x, Yx);
            Yy = fmaf(g, q.y, Yy);
            Yz = fmaf(g, q.z, Yz);
        }
    }
    Yp[tid] = make_float4(Yx, Yy, Yz, 0.f);
    __syncthreads();

    double y2d = 0.0;
    if (half == 0 && pt < NT) {
        float4 a = Yp[tid], b = Yp[tid + 128];
        float yx = a.x + b.x, yy = a.y + b.y, yz = a.z + b.z;
        float* op = out + 3*(size_t)(n0 + pt);
        op[0] = yx; op[1] = yy; op[2] = yz;
        y2d = (double)yx*yx + (double)yy*yy + (double)yz*yz;
    }
    {
        const int lane = tid & 63, wid = tid >> 6;
        #pragma unroll
        for (int off = 32; off > 0; off >>= 1) y2d += __shfl_xor(y2d, off);
        if (lane == 0) redd[wid] = y2d;
    }
    __syncthreads();
    if (tid == 0) atomicAdd(CD + 2, redd[0] + redd[1] + redd[2] + redd[3]);

    __threadfence();
    if (tid == 0) lastFlag = (atomicAdd(TK + 1, 1) == nblk - 1);
    __syncthreads();
    if (!lastFlag || tid != 0) return;

    // ===== fused pass4 =====
    double sumY2  = atomicAdd(CD + 2, 0.0);
    double sumSM2 = CD[3];
    double Cfe = (sumSM2 - sumY2) * (double)CF[7]
               + (double)N * (double)CF[1]
               + 0.69314718055994531 * (double)CF[8]
               - (double)CF[6];
    out[3*(size_t)N] = (float)Cfe;
}

extern "C" void kernel_launch(void* const* d_in, const int* in_sizes, int n_in,
                              void* d_out, int out_size, void* d_ws, size_t ws_size,
                              hipStream_t stream)
{
    const float* X     = (const float*)d_in[0];
    const float* mu    = (const float*)d_in[1];
    const float* w     = (const float*)d_in[2];
    const float* sigma = (const float*)d_in[3];
    float* out = (float*)d_out;
    float* ws  = (float*)d_ws;
    const int N = in_sizes[0] / 3;
    const int nblk = (N + TILE - 1) / TILE;

    gmm_prep <<<1,    256, 0, stream>>>(mu, w, sigma, ws);
    gmm_pass1<<<nblk, 256, 0, stream>>>(X, ws, N, nblk);
    gmm_pass3<<<nblk, 256, 0, stream>>>(X, ws, out, N, nblk);
}

// Round 4
// 145.896 us; speedup vs baseline: 3.4027x; 3.4027x over previous
//
#include <hip/hip_runtime.h>
#include <math.h>

#define CC   256   // clusters
#define TILE 256   // points per block

// float-index offsets in ws
#define OFF_P     0        // 256 x float4: (mu_x, mu_y, mu_z, alpha)
#define OFF_Q     1024     // 256 x float4: mu_new
#define OFF_S     2048     // S[256] | Ax[256] | Ay[256] | Az[256]
#define OFF_CD    3072     // 4 doubles: [0]=sumX2 [1]=sumT2 [2]=sumY2 [3]=sumSM2new
#define OFF_CF    3080     // floats: [0]=twok [1]=lgn [2]=inv2sn2 [3]=sumSlpi(ln) [4]=sumGL2(log2)
#define OFF_T2    3088     // N floats: per-point log2-normalizer

__device__ __forceinline__ float fexp2(float x) { return __builtin_amdgcn_exp2f(x); }
__device__ __forceinline__ float flog2(float x) { return __builtin_amdgcn_logf(x); }  // v_log_f32 = log2

__global__ __launch_bounds__(256) void gmm_prep(const float* __restrict__ mu,
                                                const float* __restrict__ w,
                                                const float* __restrict__ sigma,
                                                float* __restrict__ ws)
{
    __shared__ float redA[4], redB[4];
    const int c = threadIdx.x;
    const int lane = c & 63, wid = c >> 6;

    // zero per-launch accumulators (stream-ordered before pass1)
    ws[OFF_S + c] = 0.f; ws[OFF_S + 256 + c] = 0.f;
    ws[OFF_S + 512 + c] = 0.f; ws[OFF_S + 768 + c] = 0.f;
    if (c < 4) ((double*)(ws + OFF_CD))[c] = 0.0;
    if (c >= 8 && c < 16) ws[OFF_CF + (c - 6)] = 0.f;

    float wc = w[c];
    // Zw = logsumexp(w) over 256
    float m = wc;
    #pragma unroll
    for (int off = 32; off > 0; off >>= 1) m = fmaxf(m, __shfl_xor(m, off));
    if (lane == 0) redA[wid] = m;
    __syncthreads();
    m = fmaxf(fmaxf(redA[0], redA[1]), fmaxf(redA[2], redA[3]));
    float e = expf(wc - m);
    #pragma unroll
    for (int off = 32; off > 0; off >>= 1) e += __shfl_xor(e, off);
    if (lane == 0) redB[wid] = e;
    __syncthreads();
    float Zw = m + logf(redB[0] + redB[1] + redB[2] + redB[3]);

    const float L = 1.4426950408889634f;   // log2(e)
    float sig = sigma[0];
    float lgn = 3.0f * (logf(sig) + 0.91893853320467274f);  // d*(log sig + 0.5*log 2pi)
    float k = L / (2.0f * sig * sig);
    float mx = mu[3*c], my = mu[3*c+1], mz = mu[3*c+2];
    float m2 = mx*mx + my*my + mz*mz;
    float alpha = (wc - Zw - lgn) * L - k * m2;
    ((float4*)(ws + OFF_P))[c] = make_float4(mx, my, mz, alpha);
    if (c == 0) { ws[OFF_CF + 0] = 2.0f * k; ws[OFF_CF + 1] = lgn; }
}

__global__ __launch_bounds__(256) void gmm_pass1(const float* __restrict__ X,
                                                 float* __restrict__ ws, int N)
{
    __shared__ float4 Psh[CC];
    __shared__ float4 XT[TILE];     // (x,y,z, x2 -> T2)
    __shared__ double redd[2][4];

    const int tid = threadIdx.x;
    const int n0  = blockIdx.x * TILE;
    const int NT  = min(TILE, N - n0);
    const float twok = ws[OFF_CF + 0];

    Psh[tid] = ((const float4*)(ws + OFF_P))[tid];
    float x2 = 0.f;
    if (tid < NT) {
        const float* xp = X + 3*(size_t)(n0 + tid);
        float x = xp[0], y = xp[1], z = xp[2];
        x2 = fmaf(x, x, fmaf(y, y, z*z));
        XT[tid] = make_float4(x, y, z, x2);
    }
    __syncthreads();

    // phase A: one thread per point, two-pass LSE over 256 clusters
    double t2d = 0.0;
    if (tid < NT) {
        float4 xt = XT[tid];
        float m = -3.0e38f;
        #pragma unroll 8
        for (int c = 0; c < CC; ++c) {
            float4 p = Psh[c];
            float dot = fmaf(xt.x, p.x, fmaf(xt.y, p.y, xt.z * p.z));
            m = fmaxf(m, fmaf(twok, dot, p.w));
        }
        float s = 0.f;
        #pragma unroll 8
        for (int c = 0; c < CC; ++c) {
            float4 p = Psh[c];
            float dot = fmaf(xt.x, p.x, fmaf(xt.y, p.y, xt.z * p.z));
            s += fexp2(fmaf(twok, dot, p.w) - m);
        }
        float T2 = m + flog2(s);
        XT[tid].w = T2;                 // overwrite x2 with T2 for phase B
        ws[OFF_T2 + n0 + tid] = T2;
        t2d = (double)T2;
    }
    // block-reduce sumX2, sumT2 (doubles)
    {
        double xd = (double)x2;
        const int lane = tid & 63, wid = tid >> 6;
        #pragma unroll
        for (int off = 32; off > 0; off >>= 1) { xd += __shfl_xor(xd, off); t2d += __shfl_xor(t2d, off); }
        if (lane == 0) { redd[0][wid] = xd; redd[1][wid] = t2d; }
    }
    __syncthreads();
    if (tid == 0) {
        double* CD = (double*)(ws + OFF_CD);
        atomicAdd(CD + 0, redd[0][0] + redd[0][1] + redd[0][2] + redd[0][3]);
        atomicAdd(CD + 1, redd[1][0] + redd[1][1] + redd[1][2] + redd[1][3]);
    }

    // phase B: one thread per cluster over NT points (9 VALU + 1 trans + 1 ds)
    float4 p = Psh[tid];
    float S = 0.f, Ax = 0.f, Ay = 0.f, Az = 0.f;
    #pragma unroll 4
    for (int n = 0; n < NT; ++n) {
        float4 xt = XT[n];
        float dot = fmaf(xt.x, p.x, fmaf(xt.y, p.y, xt.z * p.z));
        float g = fexp2(fmaf(twok, dot, p.w) - xt.w);
        S += g;
        Ax = fmaf(g, xt.x, Ax);
        Ay = fmaf(g, xt.y, Ay);
        Az = fmaf(g, xt.z, Az);
    }
    float* Sg = ws + OFF_S;
    atomicAdd(Sg       + tid, S);
    atomicAdd(Sg + 256 + tid, Ax);
    atomicAdd(Sg + 512 + tid, Ay);
    atomicAdd(Sg + 768 + tid, Az);
}

__global__ __launch_bounds__(256) void gmm_pass2(float* __restrict__ ws, int N)
{
    __shared__ double red6[6][4];
    const int c = threadIdx.x;
    const int lane = c & 63, wid = c >> 6;
    const float twok = ws[OFF_CF + 0];
    double* CD = (double*)(ws + OFF_CD);

    float Sc  = ws[OFF_S       + c];
    float Axc = ws[OFF_S + 256 + c];
    float Ayc = ws[OFF_S + 512 + c];
    float Azc = ws[OFF_S + 768 + c];
    float4 p  = ((const float4*)(ws + OFF_P))[c];   // old mu + alpha

    float inv = 1.0f / fmaxf(Sc, 1e-37f);
    float mx = Axc * inv, my = Ayc * inv, mz = Azc * inv;
    ((float4*)(ws + OFF_Q))[c] = make_float4(mx, my, mz, 0.f);

    double v0 = (double)Sc;                                              // sumS
    double v1 = (double)Sc * (double)(mx*mx + my*my + mz*mz);            // S*||mu_new||^2
    double v2 = (double)Sc * log((double)fmaxf(Sc, 1e-37f));             // S*logS
    double v3 = (double)Sc * (double)(p.x*p.x + p.y*p.y + p.z*p.z);      // S*||mu_old||^2
    double v4 = (double)Sc * (double)p.w;                                // S*alpha
    double v5 = (double)(p.x*Axc + p.y*Ayc + p.z*Azc);                   // mu_old . A

    #pragma unroll
    for (int off = 32; off > 0; off >>= 1) {
        v0 += __shfl_xor(v0, off); v1 += __shfl_xor(v1, off); v2 += __shfl_xor(v2, off);
        v3 += __shfl_xor(v3, off); v4 += __shfl_xor(v4, off); v5 += __shfl_xor(v5, off);
    }
    if (lane == 0) { red6[0][wid]=v0; red6[1][wid]=v1; red6[2][wid]=v2;
                     red6[3][wid]=v3; red6[4][wid]=v4; red6[5][wid]=v5; }
    __syncthreads();
    if (c == 0) {
        double sumS   = red6[0][0]+red6[0][1]+red6[0][2]+red6[0][3];
        double sumSM2 = red6[1][0]+red6[1][1]+red6[1][2]+red6[1][3];
        double sumSlS = red6[2][0]+red6[2][1]+red6[2][2]+red6[2][3];
        double sumMS  = red6[3][0]+red6[3][1]+red6[3][2]+red6[3][3];
        double sumAS  = red6[4][0]+red6[4][1]+red6[4][2]+red6[4][3];
        double dotMA  = red6[5][0]+red6[5][1]+red6[5][2]+red6[5][3];
        double sumX2  = CD[0];
        double sumT2  = CD[1];
        double sumGD2 = sumX2 + sumMS - 2.0 * dotMA;          // sum gamma*D2 (old mu)
        double sn2    = sumGD2 / (3.0 * (double)N);
        ws[OFF_CF + 2] = (float)(1.0 / (2.0 * sn2));
        ws[OFF_CF + 3] = (float)(sumSlS - sumS * log(sumS));  // sum S*lpi (ln units)
        ws[OFF_CF + 4] = (float)(sumAS + (double)twok * dotMA - sumT2); // sumGL2 (log2)
        CD[3] = sumSM2;
    }
}

__global__ __launch_bounds__(256) void gmm_pass3(const float* __restrict__ X,
                                                 float* __restrict__ ws,
                                                 float* __restrict__ out, int N)
{
    __shared__ float4 Psh[CC], Qsh[CC];
    __shared__ double redd[4];

    const int tid = threadIdx.x;
    const int n0  = blockIdx.x * TILE;
    const int NT  = min(TILE, N - n0);
    const float twok = ws[OFF_CF + 0];

    Psh[tid] = ((const float4*)(ws + OFF_P))[tid];
    Qsh[tid] = ((const float4*)(ws + OFF_Q))[tid];
    __syncthreads();

    double y2d = 0.0;
    if (tid < NT) {
        const int n = n0 + tid;
        const float* xp = X + 3*(size_t)n;
        float x = xp[0], y = xp[1], z = xp[2];
        float T2 = ws[OFF_T2 + n];
        float Yx = 0.f, Yy = 0.f, Yz = 0.f;
        #pragma unroll 8
        for (int c = 0; c < CC; ++c) {
            float4 p = Psh[c];
            float dot = fmaf(x, p.x, fmaf(y, p.y, z * p.z));
            float g = fexp2(fmaf(twok, dot, p.w) - T2);
            float4 q = Qsh[c];
            Yx = fmaf(g, q.x, Yx);
            Yy = fmaf(g, q.y, Yy);
            Yz = fmaf(g, q.z, Yz);
        }
        float* op = out + 3*(size_t)n;
        op[0] = Yx; op[1] = Yy; op[2] = Yz;
        y2d = (double)Yx*Yx + (double)Yy*Yy + (double)Yz*Yz;
    }
    const int lane = tid & 63, wid = tid >> 6;
    #pragma unroll
    for (int off = 32; off > 0; off >>= 1) y2d += __shfl_xor(y2d, off);
    if (lane == 0) redd[wid] = y2d;
    __syncthreads();
    if (tid == 0) atomicAdd(((double*)(ws + OFF_CD)) + 2, redd[0] + redd[1] + redd[2] + redd[3]);
}

__global__ void gmm_pass4(float* __restrict__ ws, float* __restrict__ cfe_out, int N)
{
    if (threadIdx.x == 0) {
        double* CD = (double*)(ws + OFF_CD);
        double Cfe = (CD[3] - CD[2]) * (double)ws[OFF_CF + 2]
                   + (double)N * (double)ws[OFF_CF + 1]
                   + 0.69314718055994531 * (double)ws[OFF_CF + 4]
                   - (double)ws[OFF_CF + 3];
        cfe_out[0] = (float)Cfe;
    }
}

extern "C" void kernel_launch(void* const* d_in, const int* in_sizes, int n_in,
                              void* d_out, int out_size, void* d_ws, size_t ws_size,
                              hipStream_t stream)
{
    const float* X     = (const float*)d_in[0];
    const float* mu    = (const float*)d_in[1];
    const float* w     = (const float*)d_in[2];
    const float* sigma = (const float*)d_in[3];
    float* out = (float*)d_out;
    float* ws  = (float*)d_ws;
    const int N = in_sizes[0] / 3;
    const int nblk = (N + TILE - 1) / TILE;

    gmm_prep <<<1,    256, 0, stream>>>(mu, w, sigma, ws);
    gmm_pass1<<<nblk, 256, 0, stream>>>(X, ws, N);
    gmm_pass2<<<1,    256, 0, stream>>>(ws, N);
    gmm_pass3<<<nblk, 256, 0, stream>>>(X, ws, out, N);
    gmm_pass4<<<1,    64,  0, stream>>>(ws, out + (size_t)3 * N, N);
}